// Round 3
// baseline (480.533 us; speedup 1.0000x reference)
//
#include <hip/hip_runtime.h>

#define HH 256
#define WW 256
#define CC 32
#define HWSZ (HH * WW)
#define IMGSZ (CC * HWSZ)
#define NIMG 8
#define EPSV 1e-8f

// Wave layout: 64 lanes = one image row (4 px per lane). Edge halo values come
// from neighbor lanes via shuffle instead of extra scalar global loads.
template <bool COMPUTE_NEXT>
__global__ __launch_bounds__(256) void step_kernel(const float* __restrict__ F,
                                                   float* __restrict__ Fn,
                                                   float* __restrict__ simout)
{
    // XCD-aware remap: 512 blocks, 8 XCDs -> each XCD gets one image's 64
    // row-tiles (bijective: 512 % 8 == 0). Perf heuristic only.
    const int linear = blockIdx.y * (HH / 4) + blockIdx.x;   // 0..511
    const int remap  = (linear & 7) * 64 + (linear >> 3);    // xcd*64 + idx
    const int b      = remap >> 6;                           // image
    const int rowt   = remap & 63;                           // row-tile

    const int tx = threadIdx.x & 63;   // lane = x-position group (4 px)
    const int ty = threadIdx.x >> 6;   // wave = one row
    const int y  = (rowt << 2) + ty;
    const int x0 = tx << 2;

    const float* Fb = F + (size_t)b * IMGSZ + y * WW + x0;
    const bool ym = y > 0, yp = y < HH - 1;
    const bool xl = x0 > 0, xr = x0 < WW - 4;
    const bool rowok[3] = { ym, true, yp };
    const bool colok[6] = { xl, true, true, true, true, xr };

    float4 buf[4][3];
    auto loadch = [&](int c, int slot) {
        const float* p = Fb + c * HWSZ;
        float4 z; z.x = z.y = z.z = z.w = 0.f;
        buf[slot][0] = ym ? *reinterpret_cast<const float4*>(p - WW) : z;
        buf[slot][1] =      *reinterpret_cast<const float4*>(p);
        buf[slot][2] = yp ? *reinterpret_cast<const float4*>(p + WW) : z;
    };

    // ---------------- Pass 1: norms + neighbor dots ----------------
    float sq[3][6];
    float dotv[8][4];
#pragma unroll
    for (int r = 0; r < 3; ++r)
#pragma unroll
        for (int j = 0; j < 6; ++j) sq[r][j] = 0.f;
#pragma unroll
    for (int d = 0; d < 8; ++d)
#pragma unroll
        for (int i = 0; i < 4; ++i) dotv[d][i] = 0.f;

    loadch(0, 0); loadch(1, 1); loadch(2, 2);
#pragma unroll
    for (int c = 0; c < CC; ++c) {
        if (c + 3 < CC) loadch(c + 3, (c + 3) & 3);
        float v[3][6];
#pragma unroll
        for (int r = 0; r < 3; ++r) {
            float4 m = buf[c & 3][r];
            v[r][1] = m.x; v[r][2] = m.y; v[r][3] = m.z; v[r][4] = m.w;
            const float lm = __shfl_up(m.w, 1);    // col 4tx-1 (lane tx-1's .w)
            const float rm = __shfl_down(m.x, 1);  // col 4tx+4 (lane tx+1's .x)
            v[r][0] = xl ? lm : 0.f;
            v[r][5] = xr ? rm : 0.f;
        }
#pragma unroll
        for (int r = 0; r < 3; ++r)
#pragma unroll
            for (int j = 0; j < 6; ++j) sq[r][j] = fmaf(v[r][j], v[r][j], sq[r][j]);
        int d = 0;
#pragma unroll
        for (int dyi = 0; dyi < 3; ++dyi)
#pragma unroll
            for (int dxi = 0; dxi < 3; ++dxi) {
                if (dyi == 1 && dxi == 1) continue;
#pragma unroll
                for (int i = 0; i < 4; ++i)
                    dotv[d][i] = fmaf(v[1][i + 1], v[dyi][i + dxi], dotv[d][i]);
                ++d;
            }
    }

    float nrm[3][6];
#pragma unroll
    for (int r = 0; r < 3; ++r)
#pragma unroll
        for (int j = 0; j < 6; ++j) nrm[r][j] = sqrtf(sq[r][j]);

    float w[8][4];
    float simarr[4];
#pragma unroll
    for (int i = 0; i < 4; ++i) {
        float s[8];
        const float cn = nrm[1][i + 1];
        float tot = 0.f, cnt = 0.f;
        int d = 0;
#pragma unroll
        for (int dyi = 0; dyi < 3; ++dyi)
#pragma unroll
            for (int dxi = 0; dxi < 3; ++dxi) {
                if (dyi == 1 && dxi == 1) continue;
                const bool m = rowok[dyi] && colok[i + dxi];
                const float den = fmaxf(cn * nrm[dyi][i + dxi], EPSV);
                const float cs = dotv[d][i] / den;
                s[d] = m ? cs : 0.f;
                tot += s[d];
                cnt += m ? 1.f : 0.f;
                ++d;
            }
        simarr[i] = tot / cnt;
        if (COMPUTE_NEXT) {
            float mx = s[0];
#pragma unroll
            for (int d2 = 1; d2 < 8; ++d2) mx = fmaxf(mx, s[d2]);
            float wsum = 0.f;
#pragma unroll
            for (int d2 = 0; d2 < 8; ++d2) { w[d2][i] = __expf(s[d2] - mx); wsum += w[d2][i]; }
            const float inv = 1.f / wsum;
#pragma unroll
            for (int d2 = 0; d2 < 8; ++d2) w[d2][i] *= inv;
        }
    }
    float4 simv = { simarr[0], simarr[1], simarr[2], simarr[3] };
    *reinterpret_cast<float4*>(simout + b * HWSZ + y * WW + x0) = simv;

    // ---------------- Pass 2: weighted neighbor average ----------------
    if (COMPUTE_NEXT) {
        float* outp = Fn + (size_t)b * IMGSZ + y * WW + x0;
        loadch(0, 0); loadch(1, 1); loadch(2, 2);
#pragma unroll
        for (int c = 0; c < CC; ++c) {
            if (c + 3 < CC) loadch(c + 3, (c + 3) & 3);
            float v[3][6];
#pragma unroll
            for (int r = 0; r < 3; ++r) {
                float4 m = buf[c & 3][r];
                v[r][1] = m.x; v[r][2] = m.y; v[r][3] = m.z; v[r][4] = m.w;
                const float lm = __shfl_up(m.w, 1);
                const float rm = __shfl_down(m.x, 1);
                v[r][0] = xl ? lm : 0.f;
                v[r][5] = xr ? rm : 0.f;
            }
            float o[4] = { 0.f, 0.f, 0.f, 0.f };
            int d = 0;
#pragma unroll
            for (int dyi = 0; dyi < 3; ++dyi)
#pragma unroll
                for (int dxi = 0; dxi < 3; ++dxi) {
                    if (dyi == 1 && dxi == 1) continue;
#pragma unroll
                    for (int i = 0; i < 4; ++i)
                        o[i] = fmaf(w[d][i], v[dyi][i + dxi], o[i]);
                    ++d;
                }
            float4 ov = { o[0], o[1], o[2], o[3] };
            *reinterpret_cast<float4*>(outp + c * HWSZ) = ov;
        }
    }
}

// out[g][t][p] = 0.25 * sum_{i<4} sims[tt][4g+i][p], tt = {0,0,1,2}[t]
__global__ __launch_bounds__(256) void reduce_kernel(const float* __restrict__ sims,
                                                     float* __restrict__ out)
{
    const int idx = blockIdx.x * blockDim.x + threadIdx.x;  // 131072 float4s
    const int p4 = idx & (HWSZ / 4 - 1);
    const int t  = (idx >> 14) & 3;
    const int g  = idx >> 16;
    const int tt = (t <= 1) ? 0 : (t - 1);
    const float4* s = reinterpret_cast<const float4*>(sims) +
                      (size_t)(tt * NIMG + g * 4) * (HWSZ / 4) + p4;
    float4 a = s[0];
    float4 b = s[HWSZ / 4];
    float4 c = s[2 * (HWSZ / 4)];
    float4 d = s[3 * (HWSZ / 4)];
    float4 o;
    o.x = 0.25f * (a.x + b.x + c.x + d.x);
    o.y = 0.25f * (a.y + b.y + c.y + d.y);
    o.z = 0.25f * (a.z + b.z + c.z + d.z);
    o.w = 0.25f * (a.w + b.w + c.w + d.w);
    reinterpret_cast<float4*>(out)[idx] = o;
}

extern "C" void kernel_launch(void* const* d_in, const int* in_sizes, int n_in,
                              void* d_out, int out_size, void* d_ws, size_t ws_size,
                              hipStream_t stream)
{
    const float* F0 = (const float*)d_in[0];
    float* F1   = (float*)d_ws;                       // 64 MB
    float* F2   = F1 + (size_t)NIMG * IMGSZ;          // 64 MB
    float* sims = F2 + (size_t)NIMG * IMGSZ;          // 6 MB

    dim3 block(256);
    dim3 grid(HH / 4, NIMG);

    hipLaunchKernelGGL((step_kernel<true>),  grid, block, 0, stream, F0, F1, sims);
    hipLaunchKernelGGL((step_kernel<true>),  grid, block, 0, stream, F1, F2, sims + (size_t)NIMG * HWSZ);
    hipLaunchKernelGGL((step_kernel<false>), grid, block, 0, stream, F2, nullptr, sims + (size_t)2 * NIMG * HWSZ);

    hipLaunchKernelGGL(reduce_kernel, dim3((2 * 4 * HWSZ / 4) / 256), block, 0, stream,
                       sims, (float*)d_out);
}

// Round 4
// 140.893 us; speedup vs baseline: 3.4106x; 3.4106x over previous
//
#include <hip/hip_runtime.h>

#define HH 256
#define WW 256
#define CC 32
#define HWSZ (HH * WW)
#define IMGSZ (CC * HWSZ)
#define NIMG 8
#define EPSV 1e-8f

// Halo for one channel around this lane's 4 px. Interior x-halo comes from the
// paired-lane-aware shuffle (distance 2: same channel-half, previous px group);
// only tx==0/tx==31 lanes fall back to a predicated scalar load.
__device__ __forceinline__ void load_halo_sh(const float* __restrict__ p,
                                             bool ym, bool yp, bool xl, bool xr,
                                             int tx, float v[3][6])
{
    const bool rowok[3] = { ym, true, yp };
#pragma unroll
    for (int r = 0; r < 3; ++r) {
        const float* row = p + (r - 1) * WW;
        float4 m;
        if (rowok[r]) m = *reinterpret_cast<const float4*>(row);
        else { m.x = m.y = m.z = m.w = 0.f; }
        v[r][1] = m.x; v[r][2] = m.y; v[r][3] = m.z; v[r][4] = m.w;
        float lm = __shfl_up(m.w, 2);
        float rm = __shfl_down(m.x, 2);
        if (tx == 0)  lm = (xl && rowok[r]) ? row[-1] : 0.f;
        if (tx == 31) rm = (xr && rowok[r]) ? row[4]  : 0.f;
        v[r][0] = lm;
        v[r][5] = rm;
    }
}

__device__ __forceinline__ void acc_pass1(const float v[3][6],
                                          float sq[3][6], float dotv[8][4])
{
#pragma unroll
    for (int r = 0; r < 3; ++r)
#pragma unroll
        for (int j = 0; j < 6; ++j) sq[r][j] = fmaf(v[r][j], v[r][j], sq[r][j]);
    int d = 0;
#pragma unroll
    for (int dyi = 0; dyi < 3; ++dyi)
#pragma unroll
        for (int dxi = 0; dxi < 3; ++dxi) {
            if (dyi == 1 && dxi == 1) continue;
#pragma unroll
            for (int i = 0; i < 4; ++i)
                dotv[d][i] = fmaf(v[1][i + 1], v[dyi][i + dxi], dotv[d][i]);
            ++d;
        }
}

__device__ __forceinline__ void acc_pass2(const float v[3][6],
                                          const float w[8][4], float o[4])
{
    int d = 0;
#pragma unroll
    for (int dyi = 0; dyi < 3; ++dyi)
#pragma unroll
        for (int dxi = 0; dxi < 3; ++dxi) {
            if (dyi == 1 && dxi == 1) continue;
#pragma unroll
            for (int i = 0; i < 4; ++i)
                o[i] = fmaf(w[d][i], v[dyi][i + dxi], o[i]);
            ++d;
        }
}

// Lane pairing: lane&1 selects channel half (16 channels each), lane>>1 selects
// the 4-px group. A wave covers 128 px (half a row); a block = 4 waves = 2 rows.
template <bool COMPUTE_NEXT>
__global__ __launch_bounds__(256, 4) void step_kernel(const float* __restrict__ F,
                                                      float* __restrict__ Fn,
                                                      float* __restrict__ simout)
{
    // Bijective XCD remap: 1024 blocks, each XCD gets one image's 128 row-blocks.
    const int linear = blockIdx.y * (HH / 2) + blockIdx.x;   // 0..1023
    const int remap  = (linear & 7) * 128 + (linear >> 3);
    const int b      = remap >> 7;
    const int rowblk = remap & 127;

    const int tid  = threadIdx.x;
    const int wave = tid >> 6;
    const int lane = tid & 63;
    const int half = lane & 1;
    const int tx   = lane >> 1;            // 0..31
    const int y    = rowblk * 2 + (wave >> 1);
    const int x0   = (wave & 1) * 128 + (tx << 2);
    const int c0   = half * (CC / 2);

    const bool ym = y > 0, yp = y < HH - 1;
    const bool xl = x0 > 0, xr = x0 < WW - 4;
    const bool rowok[3] = { ym, true, yp };
    const bool colok[6] = { xl, true, true, true, true, xr };

    const float* base = F + (size_t)b * IMGSZ + (size_t)c0 * HWSZ + y * WW + x0;

    // ---------------- Pass 1: partial norms + dots over 16 channels ----------
    float sq[3][6];
    float dotv[8][4];
#pragma unroll
    for (int r = 0; r < 3; ++r)
#pragma unroll
        for (int j = 0; j < 6; ++j) sq[r][j] = 0.f;
#pragma unroll
    for (int d = 0; d < 8; ++d)
#pragma unroll
        for (int i = 0; i < 4; ++i) dotv[d][i] = 0.f;

    {
        float va[3][6], vb[3][6];
        load_halo_sh(base, ym, yp, xl, xr, tx, va);
        for (int c = 0; c < CC / 2; c += 2) {
            load_halo_sh(base + (c + 1) * HWSZ, ym, yp, xl, xr, tx, vb);
            acc_pass1(va, sq, dotv);
            if (c + 2 < CC / 2) load_halo_sh(base + (c + 2) * HWSZ, ym, yp, xl, xr, tx, va);
            acc_pass1(vb, sq, dotv);
        }
    }

    // Merge the two channel halves (paired lanes).
#pragma unroll
    for (int r = 0; r < 3; ++r)
#pragma unroll
        for (int j = 0; j < 6; ++j) sq[r][j] += __shfl_xor(sq[r][j], 1);
#pragma unroll
    for (int d = 0; d < 8; ++d)
#pragma unroll
        for (int i = 0; i < 4; ++i) dotv[d][i] += __shfl_xor(dotv[d][i], 1);

    float nrm[3][6];
#pragma unroll
    for (int r = 0; r < 3; ++r)
#pragma unroll
        for (int j = 0; j < 6; ++j) nrm[r][j] = sqrtf(sq[r][j]);

    float w[8][4];
    float simarr[4];
#pragma unroll
    for (int i = 0; i < 4; ++i) {
        float s[8];
        const float cn = nrm[1][i + 1];
        float tot = 0.f, cnt = 0.f;
        int d = 0;
#pragma unroll
        for (int dyi = 0; dyi < 3; ++dyi)
#pragma unroll
            for (int dxi = 0; dxi < 3; ++dxi) {
                if (dyi == 1 && dxi == 1) continue;
                const bool m = rowok[dyi] && colok[i + dxi];
                const float den = fmaxf(cn * nrm[dyi][i + dxi], EPSV);
                const float cs = dotv[d][i] / den;
                s[d] = m ? cs : 0.f;
                tot += s[d];
                cnt += m ? 1.f : 0.f;
                ++d;
            }
        simarr[i] = tot / cnt;
        if (COMPUTE_NEXT) {
            float mx = s[0];
#pragma unroll
            for (int d2 = 1; d2 < 8; ++d2) mx = fmaxf(mx, s[d2]);
            float wsum = 0.f;
#pragma unroll
            for (int d2 = 0; d2 < 8; ++d2) { w[d2][i] = __expf(s[d2] - mx); wsum += w[d2][i]; }
            const float inv = 1.f / wsum;
#pragma unroll
            for (int d2 = 0; d2 < 8; ++d2) w[d2][i] *= inv;
        }
    }
    if (half == 0) {
        float4 simv = { simarr[0], simarr[1], simarr[2], simarr[3] };
        *reinterpret_cast<float4*>(simout + b * HWSZ + y * WW + x0) = simv;
    }

    // ---------------- Pass 2: weighted neighbor average (own 16 channels) ----
    if (COMPUTE_NEXT) {
        float* outp = Fn + (size_t)b * IMGSZ + (size_t)c0 * HWSZ + y * WW + x0;
        float va[3][6], vb[3][6];
        load_halo_sh(base, ym, yp, xl, xr, tx, va);
        for (int c = 0; c < CC / 2; c += 2) {
            load_halo_sh(base + (c + 1) * HWSZ, ym, yp, xl, xr, tx, vb);
            {
                float o[4] = { 0.f, 0.f, 0.f, 0.f };
                acc_pass2(va, w, o);
                float4 ov = { o[0], o[1], o[2], o[3] };
                *reinterpret_cast<float4*>(outp + c * HWSZ) = ov;
            }
            if (c + 2 < CC / 2) load_halo_sh(base + (c + 2) * HWSZ, ym, yp, xl, xr, tx, va);
            {
                float o[4] = { 0.f, 0.f, 0.f, 0.f };
                acc_pass2(vb, w, o);
                float4 ov = { o[0], o[1], o[2], o[3] };
                *reinterpret_cast<float4*>(outp + (c + 1) * HWSZ) = ov;
            }
        }
    }
}

// out[g][t][p] = 0.25 * sum_{i<4} sims[tt][4g+i][p], tt = {0,0,1,2}[t]
__global__ __launch_bounds__(256) void reduce_kernel(const float* __restrict__ sims,
                                                     float* __restrict__ out)
{
    const int idx = blockIdx.x * blockDim.x + threadIdx.x;  // 131072 float4s
    const int p4 = idx & (HWSZ / 4 - 1);
    const int t  = (idx >> 14) & 3;
    const int g  = idx >> 16;
    const int tt = (t <= 1) ? 0 : (t - 1);
    const float4* s = reinterpret_cast<const float4*>(sims) +
                      (size_t)(tt * NIMG + g * 4) * (HWSZ / 4) + p4;
    float4 a = s[0];
    float4 b = s[HWSZ / 4];
    float4 c = s[2 * (HWSZ / 4)];
    float4 d = s[3 * (HWSZ / 4)];
    float4 o;
    o.x = 0.25f * (a.x + b.x + c.x + d.x);
    o.y = 0.25f * (a.y + b.y + c.y + d.y);
    o.z = 0.25f * (a.z + b.z + c.z + d.z);
    o.w = 0.25f * (a.w + b.w + c.w + d.w);
    reinterpret_cast<float4*>(out)[idx] = o;
}

extern "C" void kernel_launch(void* const* d_in, const int* in_sizes, int n_in,
                              void* d_out, int out_size, void* d_ws, size_t ws_size,
                              hipStream_t stream)
{
    const float* F0 = (const float*)d_in[0];
    float* F1   = (float*)d_ws;                       // 64 MB
    float* F2   = F1 + (size_t)NIMG * IMGSZ;          // 64 MB
    float* sims = F2 + (size_t)NIMG * IMGSZ;          // 6 MB

    dim3 block(256);
    dim3 grid(HH / 2, NIMG);

    hipLaunchKernelGGL((step_kernel<true>),  grid, block, 0, stream, F0, F1, sims);
    hipLaunchKernelGGL((step_kernel<true>),  grid, block, 0, stream, F1, F2, sims + (size_t)NIMG * HWSZ);
    hipLaunchKernelGGL((step_kernel<false>), grid, block, 0, stream, F2, nullptr, sims + (size_t)2 * NIMG * HWSZ);

    hipLaunchKernelGGL(reduce_kernel, dim3((2 * 4 * HWSZ / 4) / 256), block, 0, stream,
                       sims, (float*)d_out);
}